// Round 10
// baseline (210.013 us; speedup 1.0000x reference)
//
#include <hip/hip_runtime.h>
#include <hip/hip_fp16.h>

#define N 16384
#define B 512
#define NNZ 131072
#define KMAX 16          // ELL width; Poisson(8) tail spills to overflow list

typedef unsigned int v4u __attribute__((ext_vector_type(4)));

// ---------- math helpers ----------
__device__ __forceinline__ float rcp_(float x) {
    return __builtin_amdgcn_rcpf(x);    // raw v_rcp_f32, ~1 ulp
}
__device__ __forceinline__ float tanh_(float x) {
    // overflow-safe: exp(2x)->inf gives 1, exp(2x)->0 gives -1
    return 1.f - 2.f * rcp_(__expf(2.f * x) + 1.f);
}
__device__ __forceinline__ __half2 as_h2(unsigned int u) {
    __half2 h;
    __builtin_memcpy(&h, &u, 4);
    return h;
}
__device__ __forceinline__ unsigned int pack_h2(float a, float b) {
    __half2 h = __halves2half2(__float2half_rn(a), __float2half_rn(b));
    unsigned int u;
    __builtin_memcpy(&u, &h, 4);
    return u;
}

// ---------- inline index dtype detection ----------
// int64 little-endian with values < 16384 => every odd 32-bit word is zero.
__device__ __forceinline__ int is64_(const int* __restrict__ w) {
    int a = 1;
    #pragma unroll
    for (int i = 1; i < 16; i += 2) a &= (w[i] == 0);
    return a;
}

// ---------- fused prep: transpose + ELL build + bias pack in ONE dispatch ----------
// blocks [0, 8192)        : xT transpose (B,N) f32 -> (N,B) f16
// blocks [8192, 8704)     : fill_ell (ell pre-zeroed by memset)
// blocks [8704, 8768)     : pack gate constants
__global__ __launch_bounds__(256) void prep_kernel(
        const float* __restrict__ x, __half* __restrict__ xT,
        const int* __restrict__ w, const float* __restrict__ kern,
        int* __restrict__ counts, unsigned int* __restrict__ ell,
        uint2* __restrict__ ovf, int* __restrict__ ovf_cnt,
        const float* __restrict__ bi, const float* __restrict__ bf,
        const float* __restrict__ bo, const float* __restrict__ bg,
        float4* __restrict__ b4) {
    const int bid = blockIdx.x;
    const int t = threadIdx.x;
    if (bid < 8192) {
        // 32x32 transpose tile; threads as 32x8
        __shared__ float tile[32][33];
        int bx = (bid & 511) * 32;   // N offset
        int by = (bid >> 9) * 32;    // B offset
        int tx = t & 31, ty = t >> 5;
        #pragma unroll
        for (int i = 0; i < 32; i += 8)
            tile[ty + i][tx] = x[(size_t)(by + ty + i) * N + bx + tx];
        __syncthreads();
        #pragma unroll
        for (int i = 0; i < 32; i += 8)
            xT[(size_t)(bx + ty + i) * B + by + tx] = __float2half(tile[tx][ty + i]);
    } else if (bid < 8704) {
        int k = (bid - 8192) * 256 + t;
        int is64 = is64_(w);
        int row = is64 ? w[4 * k]     : w[2 * k];
        int col = is64 ? w[4 * k + 2] : w[2 * k + 1];
        unsigned int packed = (unsigned int)(unsigned short)row |
                              ((unsigned int)__half_as_ushort(__float2half_rn(kern[k])) << 16);
        int slot = atomicAdd(&counts[col], 1);
        if (slot < KMAX) {
            ell[col * KMAX + slot] = packed;
        } else {
            int pos = atomicAdd(ovf_cnt, 1);
            ovf[pos] = make_uint2((unsigned int)col, packed);
        }
    } else {
        // gate constants: (e^-bi, e^-bf, e^-bo, e^-2bg)
        // sigmoid(z+b) = 1/(1 + e^-b e^-z); tanh(z+bg) = 2/(1 + e^-2bg e^-2z) - 1
        int i = (bid - 8704) * 256 + t;
        b4[i] = make_float4(__expf(-bi[i]), __expf(-bf[i]), __expf(-bo[i]),
                            __expf(-2.f * bg[i]));
    }
}

// ---------- fused spmm + LSTM gates ----------
// Grid 4096 = (N/32) x 8. Block: 32 cols x 64 batch (one eighth).
//   q = blockIdx & 7 -> batch eighth; round-robin dispatch pins each q to one
//   XCD, whose L2 caches that eighth's h_in + h_out slices (2+2 MB = fits).
// c is loaded/stored NON-TEMPORAL (nt): the 32 MB/iter c stream no longer
// evicts the h gather slice from L2 -> gathers hit L2 instead of HBM.
// Thread: 1 col x 8 batch elems (uint4 = 8 f16). 8-lane col group gathers a
// contiguous 128 B row segment per entry; all 16 gathers in ONE round
// (16 outstanding misses/wave for max memory-level parallelism).
// spmm accumulates in packed f16 (v_pk_fma_f16). ELL pads are zero.
// LAST: writes transposed f32 directly to out via an LDS tile (NT stores).
template <bool FIRST, bool LAST>
__global__ __launch_bounds__(256, 4) void lstm_iter_kernel(
        const uint4*  __restrict__ hin,     // (N, B/8) packed 8xf16
        uint4*        __restrict__ hout,    // (N, B/8)
        uint4*        __restrict__ c,       // (N, B/8) packed 8xf16
        float*        __restrict__ out,     // (B, N) f32 (LAST only)
        const int*    __restrict__ counts,  // N column degrees (overflow check)
        const uint4*  __restrict__ ell4,    // N*KMAX entries as uint4
        const uint2*  __restrict__ ovf,
        const int*    __restrict__ ovf_cnt,
        const float4* __restrict__ b4) {
    const int t     = threadIdx.x;
    const int lane8 = t & 7;
    const int sub   = t >> 3;                // col within block's 32
    const int q     = blockIdx.x & 7;        // batch eighth
    const int col   = (blockIdx.x >> 3) * 32 + sub;
    const int boff  = q * 8 + lane8;         // uint4 index within a row (B/8 = 64)

    // entry words (4 x 16B, uniform per 8-lane group)
    uint4 e0 = ell4[col * 4 + 0];
    uint4 e1 = ell4[col * 4 + 1];
    uint4 e2 = ell4[col * 4 + 2];
    uint4 e3 = ell4[col * 4 + 3];
    unsigned int en[KMAX] = { e0.x, e0.y, e0.z, e0.w, e1.x, e1.y, e1.z, e1.w,
                              e2.x, e2.y, e2.z, e2.w, e3.x, e3.y, e3.z, e3.w };

    // all 16 gathers in flight simultaneously
    const v4u* hv4 = (const v4u*)hin;
    v4u hv[KMAX];
    #pragma unroll
    for (int j = 0; j < KMAX; ++j)
        hv[j] = hv4[(en[j] & 0xFFFFu) * (B / 8) + boff];

    // packed-f16 accumulators for 8 batch elems
    __half2 zp0 = __float2half2_rn(0.f), zp1 = zp0, zp2 = zp0, zp3 = zp0;
    #pragma unroll
    for (int j = 0; j < KMAX; ++j) {
        __half  vh = __ushort_as_half((unsigned short)(en[j] >> 16));
        __half2 vv = __half2half2(vh);
        zp0 = __hfma2(vv, as_h2(hv[j].x), zp0);
        zp1 = __hfma2(vv, as_h2(hv[j].y), zp1);
        zp2 = __hfma2(vv, as_h2(hv[j].z), zp2);
        zp3 = __hfma2(vv, as_h2(hv[j].w), zp3);
    }
    // rare overflow (deg > KMAX, ~0.3% of columns)
    int cnt = counts[col];
    if (cnt > KMAX) {
        int novf = *ovf_cnt;
        for (int k = 0; k < novf; ++k) {
            uint2 o = ovf[k];
            if (o.x == (unsigned int)col) {
                unsigned int p = o.y;
                __half2 vv = __half2half2(__ushort_as_half((unsigned short)(p >> 16)));
                uint4 hx = hin[(p & 0xFFFFu) * (B / 8) + boff];
                zp0 = __hfma2(vv, as_h2(hx.x), zp0);
                zp1 = __hfma2(vv, as_h2(hx.y), zp1);
                zp2 = __hfma2(vv, as_h2(hx.z), zp2);
                zp3 = __hfma2(vv, as_h2(hx.w), zp3);
            }
        }
    }

    // unpack z to f32 once
    float z[8];
    { float2 f;
      f = __half22float2(zp0); z[0] = f.x; z[1] = f.y;
      f = __half22float2(zp1); z[2] = f.x; z[3] = f.y;
      f = __half22float2(zp2); z[4] = f.x; z[5] = f.y;
      f = __half22float2(zp3); z[6] = f.x; z[7] = f.y; }

    const float4 bb = b4[col];               // (e^-bi, e^-bf, e^-bo, e^-2bg)
    const unsigned int idx = (unsigned int)col * (B / 8) + boff;

    float cv[8] = {0.f, 0.f, 0.f, 0.f, 0.f, 0.f, 0.f, 0.f};
    if (!FIRST) {
        v4u cr = __builtin_nontemporal_load((const v4u*)c + idx);
        float2 c0 = __half22float2(as_h2(cr.x));
        float2 c1 = __half22float2(as_h2(cr.y));
        float2 c2 = __half22float2(as_h2(cr.z));
        float2 c3 = __half22float2(as_h2(cr.w));
        cv[0] = c0.x; cv[1] = c0.y; cv[2] = c1.x; cv[3] = c1.y;
        cv[4] = c2.x; cv[5] = c2.y; cv[6] = c3.x; cv[7] = c3.y;
    }

    float hh[8], ch[8];
    #pragma unroll
    for (int e = 0; e < 8; ++e) {
        float ez = __expf(-z[e]);
        float ig = rcp_(fmaf(bb.x, ez, 1.f));
        float fg = rcp_(fmaf(bb.y, ez, 1.f));
        float og = rcp_(fmaf(bb.z, ez, 1.f));
        float dE = bb.w * ez * ez;
        float gg = fmaf(2.f, rcp_(1.f + dE), -1.f);   // tanh(z+bg)
        float cn = fg * cv[e] + ig * gg;
        ch[e] = cn;
        hh[e] = og * tanh_(cn);
    }

    if (!LAST) {
        v4u cw = { pack_h2(ch[0], ch[1]), pack_h2(ch[2], ch[3]),
                   pack_h2(ch[4], ch[5]), pack_h2(ch[6], ch[7]) };
        __builtin_nontemporal_store(cw, (v4u*)c + idx);
        // h_out stays NORMAL (cached): it's next iteration's gather source
        hout[idx] = make_uint4(pack_h2(hh[0], hh[1]), pack_h2(hh[2], hh[3]),
                               pack_h2(hh[4], hh[5]), pack_h2(hh[6], hh[7]));
    } else {
        // transposed f32 write: block tile = 64 batch rows x 32 cols (+1 pad)
        __shared__ float tile[64 * 33];
        #pragma unroll
        for (int e = 0; e < 8; ++e)
            tile[(lane8 * 8 + e) * 33 + sub] = hh[e];
        __syncthreads();
        const int col0 = (blockIdx.x >> 3) * 32;
        #pragma unroll
        for (int k = 0; k < 8; ++k) {
            int i = k * 256 + t;
            int r = i >> 5;        // batch row 0..63
            int cc = i & 31;       // col 0..31
            __builtin_nontemporal_store(tile[r * 33 + cc],
                                        &out[(size_t)(q * 64 + r) * N + col0 + cc]);
        }
    }
}

extern "C" void kernel_launch(void* const* d_in, const int* in_sizes, int n_in,
                              void* d_out, int out_size, void* d_ws, size_t ws_size,
                              hipStream_t stream) {
    const float* x    = (const float*)d_in[0];
    const float* kern = (const float*)d_in[1];
    const float* b_i  = (const float*)d_in[2];
    const float* b_f  = (const float*)d_in[3];
    const float* b_o  = (const float*)d_in[4];
    const float* b_g  = (const float*)d_in[5];
    const int*   idxw = (const int*)d_in[6];

    char* ws = (char*)d_ws;
    uint4*        hA      = (uint4*)       (ws + 0);          // 16777216 B
    uint4*        hB      = (uint4*)       (ws + 16777216);   // 16777216 B
    uint4*        c       = (uint4*)       (ws + 33554432);   // 16777216 B
    unsigned int* ell     = (unsigned int*)(ws + 50331648);   // 1048576 B (zeroed)
    int*          counts  = (int*)         (ws + 51380224);   // 65536 B   (zeroed)
    int*          ovf_cnt = (int*)         (ws + 51445760);   // 4 B       (zeroed)
    uint2*        ovf     = (uint2*)       (ws + 51445768);   // 32768 B
    float4*       b4      = (float4*)      (ws + 51478656);   // 262144 B (16B-aligned)

    // one memset zeroes ell + counts + ovf_cnt (contiguous)
    hipMemsetAsync(ell, 0, 1048576 + 65536 + 4, stream);

    // fused prep: transpose (8192) + fill_ell (512) + pack_bias (64)
    prep_kernel<<<8768, 256, 0, stream>>>(x, (__half*)hA, idxw, kern,
                                          counts, ell, ovf, ovf_cnt,
                                          b_i, b_f, b_o, b_g, b4);

    const uint4* ell4 = (const uint4*)ell;
    float* out = (float*)d_out;
    const int GRID = (N / 32) * 8;   // 4096

    lstm_iter_kernel<true,  false><<<GRID, 256, 0, stream>>>(hA, hB, c, out, counts, ell4, ovf, ovf_cnt, b4);
    lstm_iter_kernel<false, false><<<GRID, 256, 0, stream>>>(hB, hA, c, out, counts, ell4, ovf, ovf_cnt, b4);
    lstm_iter_kernel<false, false><<<GRID, 256, 0, stream>>>(hA, hB, c, out, counts, ell4, ovf, ovf_cnt, b4);
    // LAST: writes transposed f32 directly into d_out (hout unused)
    lstm_iter_kernel<false, true ><<<GRID, 256, 0, stream>>>(hB, hA, c, out, counts, ell4, ovf, ovf_cnt, b4);
}